// Round 3
// baseline (1517.768 us; speedup 1.0000x reference)
//
#include <hip/hip_runtime.h>
#include <hip/hip_bf16.h>
#include <math.h>

// NODE_DIM=3, EMBED=16
#define ND 3
#define EM 16
#define NR 8          // count ranges == XCD count (blockIdx % 8 ~ XCD id)
#define NRF 16        // fill ranges: 2 phases x 8 XCDs (2MB dirty window per XCD)
#define EPB 4096      // edges per block-chunk in ranged kernels (256 thr * 16)

typedef int int4v __attribute__((ext_vector_type(4)));
#define NTL(p) __builtin_nontemporal_load(p)

__device__ __forceinline__ float sp(float x) {
    // jax.nn.softplus = max(x,0) + log1p(exp(-|x|))
    return fmaxf(x, 0.0f) + log1pf(expf(-fabsf(x)));
}

// Kernel 1: x0 = softplus(pos @ W_init + b_init); xwA = x0 @ W_g1. Zero cnt.
__global__ __launch_bounds__(256) void node_init(
    const float* __restrict__ pos,
    const float* __restrict__ W_init, const float* __restrict__ b_init,
    const float* __restrict__ W_g1,
    float* __restrict__ xw, int* __restrict__ cnt, int N)
{
    __shared__ float sWi[ND * EM];
    __shared__ float sbi[EM];
    __shared__ float sW1[EM * EM];
    int t = threadIdx.x;
    if (t < ND * EM) sWi[t] = W_init[t];
    if (t < EM)      sbi[t] = b_init[t];
    sW1[t] = W_g1[t];
    __syncthreads();

    int n = blockIdx.x * 256 + t;
    if (n >= N) return;

    float p0 = pos[3 * (size_t)n + 0];
    float p1 = pos[3 * (size_t)n + 1];
    float p2 = pos[3 * (size_t)n + 2];

    float x0[EM];
#pragma unroll
    for (int j = 0; j < EM; j++) {
        float h = fmaf(p0, sWi[0 * EM + j],
                  fmaf(p1, sWi[1 * EM + j],
                  fmaf(p2, sWi[2 * EM + j], sbi[j])));
        x0[j] = sp(h);
    }
    float o[EM];
#pragma unroll
    for (int k = 0; k < EM; k++) {
        float a = 0.0f;
#pragma unroll
        for (int j = 0; j < EM; j++) a = fmaf(x0[j], sW1[j * EM + k], a);
        o[k] = a;
    }
    float4* xo = (float4*)(xw + (size_t)n * EM);
#pragma unroll
    for (int q = 0; q < 4; q++)
        xo[q] = make_float4(o[4*q+0], o[4*q+1], o[4*q+2], o[4*q+3]);
    cnt[n] = 0;
}

// Kernel 2 (ranged): in-degree count. Block group g = blockIdx%8 handles dst
// range [lo, lo+len); groups stream the whole dst array with nt loads
// (read-once, don't pollute L2), so each XCD's atomics stay in a resident
// 250KB window of cnt.
__global__ __launch_bounds__(256) void edge_count_r(
    const int* __restrict__ ei, int* __restrict__ cnt, int E, int N)
{
    int g = blockIdx.x & (NR - 1);
    int c = blockIdx.x / NR;
    int q = N / NR, r = N % NR;
    int lo  = g * q + (g < r ? g : r);
    int len = q + (g < r ? 1 : 0);
    const int* dp = ei + (size_t)E;
    int segbase = c * EPB;

    if ((E & 3) == 0) {
#pragma unroll
        for (int it = 0; it < 4; it++) {
            int e0 = segbase + it * 1024 + threadIdx.x * 4;
            if (e0 >= E) continue;
            int4v d4 = NTL((const int4v*)(dp + e0));
            if ((unsigned)(d4[0] - lo) < (unsigned)len) atomicAdd(&cnt[d4[0]], 1);
            if ((unsigned)(d4[1] - lo) < (unsigned)len) atomicAdd(&cnt[d4[1]], 1);
            if ((unsigned)(d4[2] - lo) < (unsigned)len) atomicAdd(&cnt[d4[2]], 1);
            if ((unsigned)(d4[3] - lo) < (unsigned)len) atomicAdd(&cnt[d4[3]], 1);
        }
    } else {
        for (int it = 0; it < 16; it++) {
            int e = segbase + it * 256 + threadIdx.x;
            if (e < E) {
                int d = dp[e];
                if ((unsigned)(d - lo) < (unsigned)len) atomicAdd(&cnt[d], 1);
            }
        }
    }
}

// Kernel 3a: per-block (1024 nodes) partial sums of cnt.
__global__ __launch_bounds__(256) void scan_partial(
    const int* __restrict__ cnt, int* __restrict__ bsums, int N)
{
    __shared__ int sd[256];
    int t = threadIdx.x;
    int base = blockIdx.x * 1024 + t * 4;
    int s = 0;
#pragma unroll
    for (int i = 0; i < 4; i++) { int n = base + i; if (n < N) s += cnt[n]; }
    sd[t] = s;
    __syncthreads();
    for (int off = 128; off >= 1; off >>= 1) {
        if (t < off) sd[t] += sd[t + off];
        __syncthreads();
    }
    if (t == 0) bsums[blockIdx.x] = sd[0];
}

// Kernel 3b: exclusive scan of block sums in place (NB <= 1024).
__global__ __launch_bounds__(1024) void scan_blocksums(int* __restrict__ bsums, int NB)
{
    __shared__ int sd[1024];
    int t = threadIdx.x;
    int v = (t < NB) ? bsums[t] : 0;
    sd[t] = v;
    __syncthreads();
    for (int off = 1; off < 1024; off <<= 1) {
        int add = (t >= off) ? sd[t - off] : 0;
        __syncthreads();
        sd[t] += add;
        __syncthreads();
    }
    if (t < NB) bsums[t] = sd[t] - v;  // exclusive
}

// Kernel 3c: final rowptr + cursor init.
__global__ __launch_bounds__(256) void scan_final(
    const int* __restrict__ cnt, const int* __restrict__ bsums,
    int* __restrict__ rowptr, int* __restrict__ cursor, int N, int E)
{
    __shared__ int sd[256];
    int t = threadIdx.x;
    int n0 = blockIdx.x * 1024 + t * 4;
    int c[4];
#pragma unroll
    for (int i = 0; i < 4; i++) c[i] = (n0 + i < N) ? cnt[n0 + i] : 0;
    int mysum = c[0] + c[1] + c[2] + c[3];
    sd[t] = mysum;
    __syncthreads();
    for (int off = 1; off < 256; off <<= 1) {
        int add = (t >= off) ? sd[t - off] : 0;
        __syncthreads();
        sd[t] += add;
        __syncthreads();
    }
    int r = bsums[blockIdx.x] + sd[t] - mysum;
#pragma unroll
    for (int i = 0; i < 4; i++) {
        int n = n0 + i;
        if (n < N) { rowptr[n] = r; cursor[n] = r; r += c[i]; }
    }
    if (blockIdx.x == 0 && t == 0) rowptr[N] = E;
}

// Kernel 4 (ranged+phased): scatter edge src ids into dst-sorted buckets.
// XCD affinity: x8 = blockIdx&7 (~XCD). Range's upper bit from dispatch
// PHASE: all phase-0 blocks (ranges 0..7) dispatch before phase-1 blocks
// (ranges 8..15), and only ~tens of blocks/XCD are resident at once, so
// each XCD keeps a single 2MB dirty col window live in its 4MB L2.
// Streaming dst/src reads are non-temporal so they don't evict the dirty
// lines -> each 64B col line collects its ~16 slot writes before writeback.
__global__ __launch_bounds__(256) void edge_fill_r(
    const int* __restrict__ ei, int* __restrict__ cursor,
    int* __restrict__ col, int E, int N, int nchunk)
{
    int x8 = blockIdx.x & 7;
    int qb = blockIdx.x >> 3;
    int phase = qb / nchunk;          // 0 or 1
    int c = qb - phase * nchunk;
    int g = phase * 8 + x8;           // range id in [0, NRF)
    int qd = N / NRF, r = N % NRF;
    int lo  = g * qd + (g < r ? g : r);
    int len = qd + (g < r ? 1 : 0);
    const int* dp = ei + (size_t)E;
    int segbase = c * EPB;

    if ((E & 3) == 0) {
#pragma unroll
        for (int it = 0; it < 4; it++) {
            int e0 = segbase + it * 1024 + threadIdx.x * 4;
            if (e0 >= E) continue;
            int4v d4 = NTL((const int4v*)(dp + e0));
            bool a0 = (unsigned)(d4[0] - lo) < (unsigned)len;
            bool a1 = (unsigned)(d4[1] - lo) < (unsigned)len;
            bool a2 = (unsigned)(d4[2] - lo) < (unsigned)len;
            bool a3 = (unsigned)(d4[3] - lo) < (unsigned)len;
            if (a0 | a1 | a2 | a3) {
                int4v s4 = NTL((const int4v*)(ei + e0));
                if (a0) { int slot = atomicAdd(&cursor[d4[0]], 1); col[slot] = s4[0]; }
                if (a1) { int slot = atomicAdd(&cursor[d4[1]], 1); col[slot] = s4[1]; }
                if (a2) { int slot = atomicAdd(&cursor[d4[2]], 1); col[slot] = s4[2]; }
                if (a3) { int slot = atomicAdd(&cursor[d4[3]], 1); col[slot] = s4[3]; }
            }
        }
    } else {
        for (int it = 0; it < 16; it++) {
            int e = segbase + it * 256 + threadIdx.x;
            if (e < E) {
                int d = dp[e];
                if ((unsigned)(d - lo) < (unsigned)len) {
                    int slot = atomicAdd(&cursor[d], 1);
                    col[slot] = ei[e];
                }
            }
        }
    }
}

// Kernel 5: weighted degree via gather; dinv = rsqrt(1 + sum_w).
// 16 lanes per node; lane j handles edges start+j, start+j+16, ...
// Also: (a) materializes per-edge weight w[j] (reused by both conv layers,
// removing their pos gathers); (b) scales xwA row in place by dinv[n]
// (z1 = dinv * (x0@Wg1)), removing the dinv[src] gather from the convs.
// col is a read-once stream -> nt load (protects pos table's L2 residency).
__global__ __launch_bounds__(256) void deg_gather(
    const int* __restrict__ rowptr, const int* __restrict__ col,
    const float* __restrict__ pos, float* __restrict__ w,
    float* __restrict__ dinv, float* __restrict__ xw, int N)
{
    int t = threadIdx.x;
    int lane = t & 15;
    int n = blockIdx.x * 16 + (t >> 4);
    if (n >= N) return;
    int start = rowptr[n], end = rowptr[n + 1];
    float px = pos[3 * (size_t)n + 0];
    float py = pos[3 * (size_t)n + 1];
    float pz = pos[3 * (size_t)n + 2];
    float sum = 0.0f;
    for (int j = start + lane; j < end; j += 16) {
        int s = NTL(&col[j]);
        float dx = px - pos[3 * (size_t)s + 0];
        float dy = py - pos[3 * (size_t)s + 1];
        float dz = pz - pos[3 * (size_t)s + 2];
        float d = sqrtf(fmaf(dx, dx, fmaf(dy, dy, dz * dz)));
        w[j] = d;
        sum += d;
    }
#pragma unroll
    for (int off = 8; off >= 1; off >>= 1) sum += __shfl_xor(sum, off, 64);
    float di = rsqrtf(1.0f + sum);
    if (lane == 0) dinv[n] = di;
    xw[(size_t)n * EM + lane] *= di;   // z1 = dinv * xwA (coalesced 64B row)
}

// Kernel 6 (x2): fused GCN-mean layer via gather, on pre-scaled operand
// z[s][c] = dinv[s] * xin[s][c]. Per edge: acc += w[j] * z[src][c].
// Self loop is just z[n][c]. Then x = sp(di*acc/(deg+1) + b).
// If mulW: out = (x @ W) * di (pre-scales next layer's z).
// col/w are read-once streams -> nt loads (protect z table's L2 residency).
__global__ __launch_bounds__(256) void gather_conv(
    const int* __restrict__ rowptr, const int* __restrict__ col,
    const float* __restrict__ w, const float* __restrict__ dinv,
    const float* __restrict__ z, const float* __restrict__ bconv,
    const float* __restrict__ W, float* __restrict__ xout, int N, int mulW)
{
    __shared__ float sW[EM * EM];
    __shared__ float lx[16][EM + 1];
    int t = threadIdx.x;
    sW[t] = W[t];
    int g = t >> 4, c = t & 15;
    int n = blockIdx.x * 16 + g;

    float x = 0.0f;
    float di = 1.0f;
    if (n < N) {
        int start = rowptr[n], end = rowptr[n + 1];
        di = dinv[n];
        float acc0 = z[(size_t)n * EM + c];   // self loop (pre-scaled)
        float acc1 = 0.0f;
        int j = start;
        for (; j + 1 < end; j += 2) {
            int s0 = NTL(&col[j]), s1 = NTL(&col[j + 1]);
            float w0 = NTL(&w[j]), w1 = NTL(&w[j + 1]);
            acc0 = fmaf(w0, z[(size_t)s0 * EM + c], acc0);
            acc1 = fmaf(w1, z[(size_t)s1 * EM + c], acc1);
        }
        if (j < end)
            acc0 = fmaf(NTL(&w[j]), z[(size_t)NTL(&col[j]) * EM + c], acc0);
        float acc = acc0 + acc1;
        float rc = 1.0f / (float)(end - start + 1);
        x = sp(fmaf(acc * di, rc, bconv[c]));
    }
    __syncthreads();      // sW ready
    lx[g][c] = x;
    __syncthreads();
    if (n < N) {
        if (mulW) {
            float a = 0.0f;
#pragma unroll
            for (int j = 0; j < EM; j++) a = fmaf(lx[g][j], sW[j * EM + c], a);
            xout[(size_t)n * EM + c] = a * di;   // pre-scale layer-2 operand
        } else {
            xout[(size_t)n * EM + c] = x;
        }
    }
}

// Kernel 7: dense heads: y = sp(x2 @ Wp1 + bp1); out = (y @ Wp2 + bp2)/sig.
__global__ __launch_bounds__(256) void node_out(
    const float* __restrict__ W_p1, const float* __restrict__ b_p1,
    const float* __restrict__ W_p2, const float* __restrict__ b_p2,
    const float* __restrict__ sig, const float* __restrict__ x2arr,
    float* __restrict__ out, int N)
{
    __shared__ float sP1[EM * EM];
    __shared__ float sbp1[EM];
    __shared__ float sP2[EM * ND];
    __shared__ float sbp2[ND];
    int t = threadIdx.x;
    sP1[t] = W_p1[t];
    if (t < EM)      sbp1[t] = b_p1[t];
    if (t < EM * ND) sP2[t] = W_p2[t];
    if (t < ND)      sbp2[t] = b_p2[t];
    __syncthreads();

    int n = blockIdx.x * 256 + t;
    if (n >= N) return;

    const float4* xp = (const float4*)(x2arr + (size_t)n * EM);
    float x2[EM];
#pragma unroll
    for (int q = 0; q < 4; q++) {
        float4 xv = xp[q];
        x2[4*q+0] = xv.x; x2[4*q+1] = xv.y; x2[4*q+2] = xv.z; x2[4*q+3] = xv.w;
    }
    float y[EM];
#pragma unroll
    for (int k = 0; k < EM; k++) {
        float a = sbp1[k];
#pragma unroll
        for (int j = 0; j < EM; j++) a = fmaf(x2[j], sP1[j * EM + k], a);
        y[k] = sp(a);
    }
    float rs = 1.0f / sig[n];
#pragma unroll
    for (int ch = 0; ch < ND; ch++) {
        float a = sbp2[ch];
#pragma unroll
        for (int j = 0; j < EM; j++) a = fmaf(y[j], sP2[j * ND + ch], a);
        out[(size_t)n * ND + ch] = a * rs;
    }
}

extern "C" void kernel_launch(void* const* d_in, const int* in_sizes, int n_in,
                              void* d_out, int out_size, void* d_ws, size_t ws_size,
                              hipStream_t stream) {
    const float* pos    = (const float*)d_in[0];
    const float* sig    = (const float*)d_in[1];
    const int*   ei     = (const int*)d_in[2];
    const float* W_init = (const float*)d_in[4];
    const float* b_init = (const float*)d_in[5];
    const float* W_g1   = (const float*)d_in[6];
    const float* b_g1   = (const float*)d_in[7];
    const float* W_g2   = (const float*)d_in[8];
    const float* b_g2   = (const float*)d_in[9];
    const float* W_p1   = (const float*)d_in[10];
    const float* b_p1   = (const float*)d_in[11];
    const float* W_p2   = (const float*)d_in[12];
    const float* b_p2   = (const float*)d_in[13];
    float* out = (float*)d_out;

    int N = in_sizes[0] / ND;
    int E = in_sizes[2] / 2;
    size_t Ns = (size_t)N, Es = (size_t)E;

    // Workspace layout (4B elements):
    // rowptr[N+1] | cnt[N] | col[E] | bsums[1024] | dinv[N] | xwA[16N] | xwB[16N] | w[E]
    // cursor aliases the start of xwB (dead before xwB is first written).
    int* rowptr = (int*)d_ws;
    int* cnt    = rowptr + (Ns + 1);
    int* col    = cnt + Ns;
    int* bsums  = col + Es;
    size_t off  = (Ns + 1) + Ns + Es + 1024;
    off = (off + 3) & ~(size_t)3;
    float* dinv = (float*)d_ws + off;
    size_t offA = off + Ns;
    offA = (offA + 3) & ~(size_t)3;
    float* xwA  = (float*)d_ws + offA;
    float* xwB  = xwA + Ns * EM;
    float* wbuf = xwB + Ns * EM;
    int* cursor = (int*)xwB;

    int nbN = (N + 255) / 256;
    int NBS = (N + 1023) / 1024;   // scan blocks (must be <= 1024)
    int nbG = (N + 15) / 16;       // 16 nodes per 256-thread block
    int nchunk = (E + EPB - 1) / EPB;
    int nbEc = NR * nchunk;                 // count: 8 ranges
    int nbEf = 8 * (NRF / 8) * nchunk;      // fill: 8 XCD groups x 2 phases

    node_init<<<nbN, 256, 0, stream>>>(pos, W_init, b_init, W_g1, xwA, cnt, N);
    edge_count_r<<<nbEc, 256, 0, stream>>>(ei, cnt, E, N);
    scan_partial<<<NBS, 256, 0, stream>>>(cnt, bsums, N);
    scan_blocksums<<<1, 1024, 0, stream>>>(bsums, NBS);
    scan_final<<<NBS, 256, 0, stream>>>(cnt, bsums, rowptr, cursor, N, E);
    edge_fill_r<<<nbEf, 256, 0, stream>>>(ei, cursor, col, E, N, nchunk);
    deg_gather<<<nbG, 256, 0, stream>>>(rowptr, col, pos, wbuf, dinv, xwA, N);
    gather_conv<<<nbG, 256, 0, stream>>>(rowptr, col, wbuf, dinv, xwA, b_g1, W_g2, xwB, N, 1);
    gather_conv<<<nbG, 256, 0, stream>>>(rowptr, col, wbuf, dinv, xwB, b_g2, W_g2, xwA, N, 0);
    node_out<<<nbN, 256, 0, stream>>>(W_p1, b_p1, W_p2, b_p2, sig, xwA, out, N);
}

// Round 4
// 1006.608 us; speedup vs baseline: 1.5078x; 1.5078x over previous
//
#include <hip/hip_runtime.h>
#include <hip/hip_bf16.h>
#include <math.h>

// NODE_DIM=3, EMBED=16
#define ND 3
#define EM 16
#define BQ 512        // nodes per bucket (power of 2)
#define BQ_SH 9
#define MAXB 1024     // max buckets => supports N <= 524288
#define CHK 8192      // edges per edge_bin block (32 per thread)
#define COLS 12288    // LDS col staging bound (mean bucket edges ~8192, +45 sigma)

__device__ __forceinline__ float sp(float x) {
    // jax.nn.softplus = max(x,0) + log1p(exp(-|x|))
    return fmaxf(x, 0.0f) + log1pf(expf(-fabsf(x)));
}

// Kernel 0: zero bucket counters.
__global__ __launch_bounds__(1024) void bucket_zero(int* __restrict__ bcnt)
{
    bcnt[threadIdx.x] = 0;
}

// Kernel A: bucket histogram of dst (bucket = dst >> 9). ONE pass over dst
// (32MB), LDS-aggregated, ~1k global atomics per block.
__global__ __launch_bounds__(256) void bucket_count(
    const int* __restrict__ ei, int* __restrict__ bcnt, int E, int NB)
{
    __shared__ int h[MAXB];
    int t = threadIdx.x;
    for (int i = t; i < MAXB; i += 256) h[i] = 0;
    __syncthreads();
    const int* dp = ei + (size_t)E;
    for (int e = blockIdx.x * 256 + t; e < E; e += gridDim.x * 256)
        atomicAdd(&h[((unsigned)dp[e]) >> BQ_SH], 1);
    __syncthreads();
    for (int i = t; i < NB; i += 256) {
        int v = h[i];
        if (v) atomicAdd(&bcnt[i], v);
    }
}

// Kernel B: exclusive scan of bucket counts (NB <= 1024) -> gbase, gcur.
__global__ __launch_bounds__(1024) void bucket_scan(
    const int* __restrict__ bcnt, int* __restrict__ gbase,
    int* __restrict__ gcur, int NB)
{
    __shared__ int sd[1024];
    int t = threadIdx.x;
    int v = (t < NB) ? bcnt[t] : 0;
    sd[t] = v;
    __syncthreads();
    for (int off = 1; off < 1024; off <<= 1) {
        int add = (t >= off) ? sd[t - off] : 0;
        __syncthreads();
        sd[t] += add;
        __syncthreads();
    }
    if (t < NB) { int ex = sd[t] - v; gbase[t] = ex; gcur[t] = ex; }
}

// Kernel C: bin edges into bucket-contiguous (src,dst) pair runs.
// Per block: LDS histogram of its 8192-edge chunk, ONE global atomicAdd per
// touched bucket reserves a contiguous run (~8 pairs = ~64B -> near-full-line
// writes), then pairs are written into the run. No per-node state.
__global__ __launch_bounds__(256) void edge_bin(
    const int* __restrict__ ei, int* __restrict__ gcur,
    int2* __restrict__ pairs, int E)
{
    __shared__ int lcnt[MAXB];
    __shared__ int sbase[MAXB];
    int t = threadIdx.x;
    for (int i = t; i < MAXB; i += 256) lcnt[i] = 0;
    __syncthreads();
    const int* dp = ei + (size_t)E;
    int c0 = blockIdx.x * CHK;
#pragma unroll 4
    for (int it = 0; it < CHK / 256; it++) {
        int e = c0 + it * 256 + t;
        if (e < E) atomicAdd(&lcnt[((unsigned)dp[e]) >> BQ_SH], 1);
    }
    __syncthreads();
    for (int i = t; i < MAXB; i += 256) {
        int v = lcnt[i];
        sbase[i] = v ? atomicAdd(&gcur[i], v) : 0;
        lcnt[i] = 0;   // reuse as local cursor
    }
    __syncthreads();
#pragma unroll 4
    for (int it = 0; it < CHK / 256; it++) {
        int e = c0 + it * 256 + t;
        if (e < E) {
            int s = ei[e];
            int d = dp[e];
            int b = ((unsigned)d) >> BQ_SH;
            int pos = sbase[b] + atomicAdd(&lcnt[b], 1);
            pairs[pos] = make_int2(s, d);
        }
    }
}

// Kernel D: per-bucket CSR build, all global writes coalesced.
// One block per bucket (512 nodes, ~8192 edges): LDS per-node histogram ->
// LDS scan -> rowptr slice (coalesced); scatter src into LDS staging via
// LDS atomics; flush col (coalesced). Fallback to direct global scatter if
// a bucket exceeds COLS (never at Poisson(8192)).
__global__ __launch_bounds__(256) void bucket_csr(
    const int2* __restrict__ pairs, const int* __restrict__ gbase,
    const int* __restrict__ bcnt, int* __restrict__ rowptr,
    int* __restrict__ col, int N, int NB)
{
    __shared__ int ncnt[BQ];
    __shared__ int ncur[BQ];
    __shared__ int sd[256];
    __shared__ int colS[COLS];
    int b = blockIdx.x;
    int t = threadIdx.x;
    int lo = b << BQ_SH;
    int hi = min(lo + BQ, N);
    int r0 = gbase[b];
    int cntE = bcnt[b];
    ncnt[2 * t] = 0;
    ncnt[2 * t + 1] = 0;
    __syncthreads();
    for (int i = t; i < cntE; i += 256)
        atomicAdd(&ncnt[pairs[r0 + i].y - lo], 1);
    __syncthreads();
    // exclusive scan over 512 (2 per thread)
    int a0 = ncnt[2 * t], a1 = ncnt[2 * t + 1];
    int s2 = a0 + a1;
    sd[t] = s2;
    __syncthreads();
    for (int off = 1; off < 256; off <<= 1) {
        int add = (t >= off) ? sd[t - off] : 0;
        __syncthreads();
        sd[t] += add;
        __syncthreads();
    }
    int ex = sd[t] - s2;          // exclusive base for node 2t
    ncur[2 * t] = ex;
    ncur[2 * t + 1] = ex + a0;
    if (lo + 2 * t < hi)     rowptr[lo + 2 * t]     = r0 + ex;
    if (lo + 2 * t + 1 < hi) rowptr[lo + 2 * t + 1] = r0 + ex + a0;
    if (b == NB - 1 && t == 0) rowptr[N] = r0 + cntE;  // == E
    __syncthreads();
    bool fit = (cntE <= COLS);
    for (int i = t; i < cntE; i += 256) {
        int2 p = pairs[r0 + i];
        int slot = atomicAdd(&ncur[p.y - lo], 1);
        if (fit) colS[slot] = p.x;
        else     col[r0 + slot] = p.x;
    }
    __syncthreads();
    if (fit)
        for (int i = t; i < cntE; i += 256) col[r0 + i] = colS[i];
}

// Kernel 1: x0 = softplus(pos @ W_init + b_init); xwA = x0 @ W_g1.
__global__ __launch_bounds__(256) void node_init(
    const float* __restrict__ pos,
    const float* __restrict__ W_init, const float* __restrict__ b_init,
    const float* __restrict__ W_g1,
    float* __restrict__ xw, int N)
{
    __shared__ float sWi[ND * EM];
    __shared__ float sbi[EM];
    __shared__ float sW1[EM * EM];
    int t = threadIdx.x;
    if (t < ND * EM) sWi[t] = W_init[t];
    if (t < EM)      sbi[t] = b_init[t];
    sW1[t] = W_g1[t];
    __syncthreads();

    int n = blockIdx.x * 256 + t;
    if (n >= N) return;

    float p0 = pos[3 * (size_t)n + 0];
    float p1 = pos[3 * (size_t)n + 1];
    float p2 = pos[3 * (size_t)n + 2];

    float x0[EM];
#pragma unroll
    for (int j = 0; j < EM; j++) {
        float h = fmaf(p0, sWi[0 * EM + j],
                  fmaf(p1, sWi[1 * EM + j],
                  fmaf(p2, sWi[2 * EM + j], sbi[j])));
        x0[j] = sp(h);
    }
    float o[EM];
#pragma unroll
    for (int k = 0; k < EM; k++) {
        float a = 0.0f;
#pragma unroll
        for (int j = 0; j < EM; j++) a = fmaf(x0[j], sW1[j * EM + k], a);
        o[k] = a;
    }
    float4* xo = (float4*)(xw + (size_t)n * EM);
#pragma unroll
    for (int q = 0; q < 4; q++)
        xo[q] = make_float4(o[4*q+0], o[4*q+1], o[4*q+2], o[4*q+3]);
}

// Kernel 5: weighted degree via gather; dinv = rsqrt(1 + sum_w).
// Materializes per-edge w[j]; scales xwA row in place by dinv[n].
__global__ __launch_bounds__(256) void deg_gather(
    const int* __restrict__ rowptr, const int* __restrict__ col,
    const float* __restrict__ pos, float* __restrict__ w,
    float* __restrict__ dinv, float* __restrict__ xw, int N)
{
    int t = threadIdx.x;
    int lane = t & 15;
    int n = blockIdx.x * 16 + (t >> 4);
    if (n >= N) return;
    int start = rowptr[n], end = rowptr[n + 1];
    float px = pos[3 * (size_t)n + 0];
    float py = pos[3 * (size_t)n + 1];
    float pz = pos[3 * (size_t)n + 2];
    float sum = 0.0f;
    for (int j = start + lane; j < end; j += 16) {
        int s = col[j];
        float dx = px - pos[3 * (size_t)s + 0];
        float dy = py - pos[3 * (size_t)s + 1];
        float dz = pz - pos[3 * (size_t)s + 2];
        float d = sqrtf(fmaf(dx, dx, fmaf(dy, dy, dz * dz)));
        w[j] = d;
        sum += d;
    }
#pragma unroll
    for (int off = 8; off >= 1; off >>= 1) sum += __shfl_xor(sum, off, 64);
    float di = rsqrtf(1.0f + sum);
    if (lane == 0) dinv[n] = di;
    xw[(size_t)n * EM + lane] *= di;   // z1 = dinv * xwA (coalesced 64B row)
}

// Kernel 6 (x2): fused GCN-mean layer via gather on pre-scaled operand
// z[s][c] = dinv[s]*xin[s][c]. acc += w[j]*z[src][c]; self loop = z[n][c];
// x = sp(di*acc/(deg+1) + b). If mulW: out = (x @ W) * di.
__global__ __launch_bounds__(256) void gather_conv(
    const int* __restrict__ rowptr, const int* __restrict__ col,
    const float* __restrict__ w, const float* __restrict__ dinv,
    const float* __restrict__ z, const float* __restrict__ bconv,
    const float* __restrict__ W, float* __restrict__ xout, int N, int mulW)
{
    __shared__ float sW[EM * EM];
    __shared__ float lx[16][EM + 1];
    int t = threadIdx.x;
    sW[t] = W[t];
    int g = t >> 4, c = t & 15;
    int n = blockIdx.x * 16 + g;

    float x = 0.0f;
    float di = 1.0f;
    if (n < N) {
        int start = rowptr[n], end = rowptr[n + 1];
        di = dinv[n];
        float acc0 = z[(size_t)n * EM + c];   // self loop (pre-scaled)
        float acc1 = 0.0f;
        int j = start;
        for (; j + 1 < end; j += 2) {
            int s0 = col[j], s1 = col[j + 1];
            float w0 = w[j], w1 = w[j + 1];
            acc0 = fmaf(w0, z[(size_t)s0 * EM + c], acc0);
            acc1 = fmaf(w1, z[(size_t)s1 * EM + c], acc1);
        }
        if (j < end)
            acc0 = fmaf(w[j], z[(size_t)col[j] * EM + c], acc0);
        float acc = acc0 + acc1;
        float rc = 1.0f / (float)(end - start + 1);
        x = sp(fmaf(acc * di, rc, bconv[c]));
    }
    __syncthreads();      // sW ready
    lx[g][c] = x;
    __syncthreads();
    if (n < N) {
        if (mulW) {
            float a = 0.0f;
#pragma unroll
            for (int j = 0; j < EM; j++) a = fmaf(lx[g][j], sW[j * EM + c], a);
            xout[(size_t)n * EM + c] = a * di;   // pre-scale layer-2 operand
        } else {
            xout[(size_t)n * EM + c] = x;
        }
    }
}

// Kernel 7: dense heads: y = sp(x2 @ Wp1 + bp1); out = (y @ Wp2 + bp2)/sig.
__global__ __launch_bounds__(256) void node_out(
    const float* __restrict__ W_p1, const float* __restrict__ b_p1,
    const float* __restrict__ W_p2, const float* __restrict__ b_p2,
    const float* __restrict__ sig, const float* __restrict__ x2arr,
    float* __restrict__ out, int N)
{
    __shared__ float sP1[EM * EM];
    __shared__ float sbp1[EM];
    __shared__ float sP2[EM * ND];
    __shared__ float sbp2[ND];
    int t = threadIdx.x;
    sP1[t] = W_p1[t];
    if (t < EM)      sbp1[t] = b_p1[t];
    if (t < EM * ND) sP2[t] = W_p2[t];
    if (t < ND)      sbp2[t] = b_p2[t];
    __syncthreads();

    int n = blockIdx.x * 256 + t;
    if (n >= N) return;

    const float4* xp = (const float4*)(x2arr + (size_t)n * EM);
    float x2[EM];
#pragma unroll
    for (int q = 0; q < 4; q++) {
        float4 xv = xp[q];
        x2[4*q+0] = xv.x; x2[4*q+1] = xv.y; x2[4*q+2] = xv.z; x2[4*q+3] = xv.w;
    }
    float y[EM];
#pragma unroll
    for (int k = 0; k < EM; k++) {
        float a = sbp1[k];
#pragma unroll
        for (int j = 0; j < EM; j++) a = fmaf(x2[j], sP1[j * EM + k], a);
        y[k] = sp(a);
    }
    float rs = 1.0f / sig[n];
#pragma unroll
    for (int ch = 0; ch < ND; ch++) {
        float a = sbp2[ch];
#pragma unroll
        for (int j = 0; j < EM; j++) a = fmaf(y[j], sP2[j * ND + ch], a);
        out[(size_t)n * ND + ch] = a * rs;
    }
}

extern "C" void kernel_launch(void* const* d_in, const int* in_sizes, int n_in,
                              void* d_out, int out_size, void* d_ws, size_t ws_size,
                              hipStream_t stream) {
    const float* pos    = (const float*)d_in[0];
    const float* sig    = (const float*)d_in[1];
    const int*   ei     = (const int*)d_in[2];
    const float* W_init = (const float*)d_in[4];
    const float* b_init = (const float*)d_in[5];
    const float* W_g1   = (const float*)d_in[6];
    const float* b_g1   = (const float*)d_in[7];
    const float* W_g2   = (const float*)d_in[8];
    const float* b_g2   = (const float*)d_in[9];
    const float* W_p1   = (const float*)d_in[10];
    const float* b_p1   = (const float*)d_in[11];
    const float* W_p2   = (const float*)d_in[12];
    const float* b_p2   = (const float*)d_in[13];
    float* out = (float*)d_out;

    int N = in_sizes[0] / ND;
    int E = in_sizes[2] / 2;
    size_t Ns = (size_t)N, Es = (size_t)E;
    int NB = (N + BQ - 1) >> BQ_SH;   // <= MAXB for N <= 524288

    // Workspace layout (4B elements):
    // rowptr[N+1] | col[E] | bcnt[1024] | gbase[1024] | gcur[1024]
    //   | dinv[N] | xwA[16N] | xwB[16N] | wbuf[E]
    // pairs[E] (int2) aliases xwA..xwB (dead before node_init writes xwA).
    int* rowptr = (int*)d_ws;
    int* col    = rowptr + (Ns + 1);
    int* bcnt   = col + Es;
    int* gbase  = bcnt + 1024;
    int* gcur   = gbase + 1024;
    size_t off  = (Ns + 1) + Es + 3 * 1024;
    off = (off + 3) & ~(size_t)3;
    float* dinv = (float*)d_ws + off;
    size_t offA = off + Ns;
    offA = (offA + 3) & ~(size_t)3;
    float* xwA  = (float*)d_ws + offA;
    float* xwB  = xwA + Ns * EM;
    float* wbuf = xwB + Ns * EM;
    int2* pairs = (int2*)xwA;

    int nbN = (N + 255) / 256;
    int nbG = (N + 15) / 16;            // 16 nodes per 256-thread block
    int nbBin = (E + CHK - 1) / CHK;

    bucket_zero<<<1, 1024, 0, stream>>>(bcnt);
    bucket_count<<<1024, 256, 0, stream>>>(ei, bcnt, E, NB);
    bucket_scan<<<1, 1024, 0, stream>>>(bcnt, gbase, gcur, NB);
    edge_bin<<<nbBin, 256, 0, stream>>>(ei, gcur, pairs, E);
    bucket_csr<<<NB, 256, 0, stream>>>(pairs, gbase, bcnt, rowptr, col, N, NB);
    node_init<<<nbN, 256, 0, stream>>>(pos, W_init, b_init, W_g1, xwA, N);
    deg_gather<<<nbG, 256, 0, stream>>>(rowptr, col, pos, wbuf, dinv, xwA, N);
    gather_conv<<<nbG, 256, 0, stream>>>(rowptr, col, wbuf, dinv, xwA, b_g1, W_g2, xwB, N, 1);
    gather_conv<<<nbG, 256, 0, stream>>>(rowptr, col, wbuf, dinv, xwB, b_g2, W_g2, xwA, N, 0);
    node_out<<<nbN, 256, 0, stream>>>(W_p1, b_p1, W_p2, b_p2, sig, xwA, out, N);
}

// Round 5
// 914.094 us; speedup vs baseline: 1.6604x; 1.1012x over previous
//
#include <hip/hip_runtime.h>
#include <hip/hip_bf16.h>
#include <math.h>

// NODE_DIM=3, EMBED=16
#define ND 3
#define EM 16
#define BQ 512        // nodes per bucket (power of 2)
#define BQ_SH 9
#define MAXB 1024     // max buckets => supports N <= 524288
#define CHK 8192      // edges per edge_bin block (32 per thread)
#define COLS 12288    // LDS col staging bound (mean bucket edges ~8192, +45 sigma)
// packed pair: (dst & 511) << 23 | src   (requires src < 2^23)
#define P_SH 23

__device__ __forceinline__ float sp(float x) {
    // jax.nn.softplus = max(x,0) + log1p(exp(-|x|))
    return fmaxf(x, 0.0f) + log1pf(expf(-fabsf(x)));
}

// Kernel 0: zero bucket counters.
__global__ __launch_bounds__(1024) void bucket_zero(int* __restrict__ bcnt)
{
    bcnt[threadIdx.x] = 0;
}

// Kernel A: bucket histogram of dst (bucket = dst >> 9). ONE pass over dst
// (32MB), LDS-aggregated, ~1k global atomics per block.
__global__ __launch_bounds__(256) void bucket_count(
    const int* __restrict__ ei, int* __restrict__ bcnt, int E, int NB)
{
    __shared__ int h[MAXB];
    int t = threadIdx.x;
    for (int i = t; i < MAXB; i += 256) h[i] = 0;
    __syncthreads();
    const int* dp = ei + (size_t)E;
    for (int e = blockIdx.x * 256 + t; e < E; e += gridDim.x * 256)
        atomicAdd(&h[((unsigned)dp[e]) >> BQ_SH], 1);
    __syncthreads();
    for (int i = t; i < NB; i += 256) {
        int v = h[i];
        if (v) atomicAdd(&bcnt[i], v);
    }
}

// Kernel B: exclusive scan of bucket counts (NB <= 1024) -> gbase, gcur.
__global__ __launch_bounds__(1024) void bucket_scan(
    const int* __restrict__ bcnt, int* __restrict__ gbase,
    int* __restrict__ gcur, int NB)
{
    __shared__ int sd[1024];
    int t = threadIdx.x;
    int v = (t < NB) ? bcnt[t] : 0;
    sd[t] = v;
    __syncthreads();
    for (int off = 1; off < 1024; off <<= 1) {
        int add = (t >= off) ? sd[t - off] : 0;
        __syncthreads();
        sd[t] += add;
        __syncthreads();
    }
    if (t < NB) { int ex = sd[t] - v; gbase[t] = ex; gcur[t] = ex; }
}

// Kernel C: bin edges into bucket-contiguous packed-pair runs, with the
// chunk SORTED IN LDS first so global writes are in-order & coalesced.
// Per block (8192 edges): dst cached in 32 VGPRs (one HBM read of dst),
// LDS histogram -> LDS scan -> one global atomicAdd per touched bucket
// reserves runs -> LDS scatter of packed (ldst<<23|src) into stage[] with
// u16 bucket-id per slot -> sequential write-out: consecutive threads hit
// consecutive addresses within each run (no partial-line scatter).
__global__ __launch_bounds__(256) void edge_bin(
    const int* __restrict__ ei, int* __restrict__ gcur,
    unsigned int* __restrict__ pairs, int E)
{
    __shared__ int lcnt[MAXB];            // histogram, then local cursor
    __shared__ int lbase[MAXB];           // local exclusive base
    __shared__ int sbase[MAXB];           // global run base
    __shared__ unsigned int stage[CHK];   // bucket-sorted packed payloads
    __shared__ unsigned short bid[CHK];   // bucket id per staged slot
    __shared__ int sd[256];
    int t = threadIdx.x;
    int c0 = blockIdx.x * CHK;
    int cntT = min(CHK, E - c0);
    for (int i = t; i < MAXB; i += 256) lcnt[i] = 0;
    __syncthreads();
    const int* dp = ei + (size_t)E;
    int dreg[32];
#pragma unroll
    for (int it = 0; it < 32; it++) {
        int e = c0 + it * 256 + t;
        dreg[it] = (e < E) ? dp[e] : 0;
        if (e < E) atomicAdd(&lcnt[((unsigned)dreg[it]) >> BQ_SH], 1);
    }
    __syncthreads();
    // exclusive scan of lcnt[1024] (4 per thread) -> lbase; reserve runs.
    int b4 = t * 4;
    int h0 = lcnt[b4], h1 = lcnt[b4 + 1], h2 = lcnt[b4 + 2], h3 = lcnt[b4 + 3];
    int s4 = h0 + h1 + h2 + h3;
    sd[t] = s4;
    __syncthreads();
    for (int off = 1; off < 256; off <<= 1) {
        int add = (t >= off) ? sd[t - off] : 0;
        __syncthreads();
        sd[t] += add;
        __syncthreads();
    }
    int ex = sd[t] - s4;
    lbase[b4]     = ex;
    lbase[b4 + 1] = ex + h0;
    lbase[b4 + 2] = ex + h0 + h1;
    lbase[b4 + 3] = ex + h0 + h1 + h2;
    sbase[b4]     = h0 ? atomicAdd(&gcur[b4], h0)     : 0;
    sbase[b4 + 1] = h1 ? atomicAdd(&gcur[b4 + 1], h1) : 0;
    sbase[b4 + 2] = h2 ? atomicAdd(&gcur[b4 + 2], h2) : 0;
    sbase[b4 + 3] = h3 ? atomicAdd(&gcur[b4 + 3], h3) : 0;
    lcnt[b4] = 0; lcnt[b4 + 1] = 0; lcnt[b4 + 2] = 0; lcnt[b4 + 3] = 0;
    __syncthreads();
    // scatter into LDS stage (bucket-sorted order)
#pragma unroll
    for (int it = 0; it < 32; it++) {
        int e = c0 + it * 256 + t;
        if (e < E) {
            int d = dreg[it];
            unsigned b = ((unsigned)d) >> BQ_SH;
            int s = ei[e];
            int pos = lbase[b] + atomicAdd(&lcnt[b], 1);
            stage[pos] = ((unsigned)(d & (BQ - 1)) << P_SH) | (unsigned)s;
            bid[pos] = (unsigned short)b;
        }
    }
    __syncthreads();
    // in-order write-out: consecutive threads -> consecutive addresses
    for (int i = t; i < cntT; i += 256) {
        unsigned b = bid[i];
        pairs[sbase[b] + (i - lbase[b])] = stage[i];
    }
}

// Kernel D: per-bucket CSR build, all global writes coalesced.
// One block per bucket (512 nodes, ~8192 edges): LDS per-node histogram ->
// LDS scan -> rowptr slice (coalesced); scatter src into LDS staging via
// LDS atomics; flush col (coalesced). Fallback to direct global scatter if
// a bucket exceeds COLS (never at Poisson(8192)).
__global__ __launch_bounds__(256) void bucket_csr(
    const unsigned int* __restrict__ pairs, const int* __restrict__ gbase,
    const int* __restrict__ bcnt, int* __restrict__ rowptr,
    int* __restrict__ col, int N, int NB)
{
    __shared__ int ncnt[BQ];
    __shared__ int ncur[BQ];
    __shared__ int sd[256];
    __shared__ int colS[COLS];
    int b = blockIdx.x;
    int t = threadIdx.x;
    int lo = b << BQ_SH;
    int hi = min(lo + BQ, N);
    int r0 = gbase[b];
    int cntE = bcnt[b];
    ncnt[2 * t] = 0;
    ncnt[2 * t + 1] = 0;
    __syncthreads();
    for (int i = t; i < cntE; i += 256)
        atomicAdd(&ncnt[pairs[r0 + i] >> P_SH], 1);
    __syncthreads();
    // exclusive scan over 512 (2 per thread)
    int a0 = ncnt[2 * t], a1 = ncnt[2 * t + 1];
    int s2 = a0 + a1;
    sd[t] = s2;
    __syncthreads();
    for (int off = 1; off < 256; off <<= 1) {
        int add = (t >= off) ? sd[t - off] : 0;
        __syncthreads();
        sd[t] += add;
        __syncthreads();
    }
    int ex = sd[t] - s2;          // exclusive base for node 2t
    ncur[2 * t] = ex;
    ncur[2 * t + 1] = ex + a0;
    if (lo + 2 * t < hi)     rowptr[lo + 2 * t]     = r0 + ex;
    if (lo + 2 * t + 1 < hi) rowptr[lo + 2 * t + 1] = r0 + ex + a0;
    if (b == NB - 1 && t == 0) rowptr[N] = r0 + cntE;  // == E
    __syncthreads();
    bool fit = (cntE <= COLS);
    for (int i = t; i < cntE; i += 256) {
        unsigned p = pairs[r0 + i];
        int slot = atomicAdd(&ncur[p >> P_SH], 1);
        int srcv = (int)(p & ((1u << P_SH) - 1));
        if (fit) colS[slot] = srcv;
        else     col[r0 + slot] = srcv;
    }
    __syncthreads();
    if (fit)
        for (int i = t; i < cntE; i += 256) col[r0 + i] = colS[i];
}

// Kernel 1: x0 = softplus(pos @ W_init + b_init); xwA = x0 @ W_g1.
__global__ __launch_bounds__(256) void node_init(
    const float* __restrict__ pos,
    const float* __restrict__ W_init, const float* __restrict__ b_init,
    const float* __restrict__ W_g1,
    float* __restrict__ xw, int N)
{
    __shared__ float sWi[ND * EM];
    __shared__ float sbi[EM];
    __shared__ float sW1[EM * EM];
    int t = threadIdx.x;
    if (t < ND * EM) sWi[t] = W_init[t];
    if (t < EM)      sbi[t] = b_init[t];
    sW1[t] = W_g1[t];
    __syncthreads();

    int n = blockIdx.x * 256 + t;
    if (n >= N) return;

    float p0 = pos[3 * (size_t)n + 0];
    float p1 = pos[3 * (size_t)n + 1];
    float p2 = pos[3 * (size_t)n + 2];

    float x0[EM];
#pragma unroll
    for (int j = 0; j < EM; j++) {
        float h = fmaf(p0, sWi[0 * EM + j],
                  fmaf(p1, sWi[1 * EM + j],
                  fmaf(p2, sWi[2 * EM + j], sbi[j])));
        x0[j] = sp(h);
    }
    float o[EM];
#pragma unroll
    for (int k = 0; k < EM; k++) {
        float a = 0.0f;
#pragma unroll
        for (int j = 0; j < EM; j++) a = fmaf(x0[j], sW1[j * EM + k], a);
        o[k] = a;
    }
    float4* xo = (float4*)(xw + (size_t)n * EM);
#pragma unroll
    for (int q = 0; q < 4; q++)
        xo[q] = make_float4(o[4*q+0], o[4*q+1], o[4*q+2], o[4*q+3]);
}

// Kernel 5: weighted degree via gather; dinv = rsqrt(1 + sum_w).
// Materializes per-edge w[j]; scales xwA row in place by dinv[n].
__global__ __launch_bounds__(256) void deg_gather(
    const int* __restrict__ rowptr, const int* __restrict__ col,
    const float* __restrict__ pos, float* __restrict__ w,
    float* __restrict__ dinv, float* __restrict__ xw, int N)
{
    int t = threadIdx.x;
    int lane = t & 15;
    int n = blockIdx.x * 16 + (t >> 4);
    if (n >= N) return;
    int start = rowptr[n], end = rowptr[n + 1];
    float px = pos[3 * (size_t)n + 0];
    float py = pos[3 * (size_t)n + 1];
    float pz = pos[3 * (size_t)n + 2];
    float sum = 0.0f;
    for (int j = start + lane; j < end; j += 16) {
        int s = col[j];
        float dx = px - pos[3 * (size_t)s + 0];
        float dy = py - pos[3 * (size_t)s + 1];
        float dz = pz - pos[3 * (size_t)s + 2];
        float d = sqrtf(fmaf(dx, dx, fmaf(dy, dy, dz * dz)));
        w[j] = d;
        sum += d;
    }
#pragma unroll
    for (int off = 8; off >= 1; off >>= 1) sum += __shfl_xor(sum, off, 64);
    float di = rsqrtf(1.0f + sum);
    if (lane == 0) dinv[n] = di;
    xw[(size_t)n * EM + lane] *= di;   // z1 = dinv * xwA (coalesced 64B row)
}

// Kernel 6 (x2): fused GCN-mean layer via gather on pre-scaled operand
// z[s][c] = dinv[s]*xin[s][c]. acc += w[j]*z[src][c]; self loop = z[n][c];
// x = sp(di*acc/(deg+1) + b). If mulW: out = (x @ W) * di.
__global__ __launch_bounds__(256) void gather_conv(
    const int* __restrict__ rowptr, const int* __restrict__ col,
    const float* __restrict__ w, const float* __restrict__ dinv,
    const float* __restrict__ z, const float* __restrict__ bconv,
    const float* __restrict__ W, float* __restrict__ xout, int N, int mulW)
{
    __shared__ float sW[EM * EM];
    __shared__ float lx[16][EM + 1];
    int t = threadIdx.x;
    sW[t] = W[t];
    int g = t >> 4, c = t & 15;
    int n = blockIdx.x * 16 + g;

    float x = 0.0f;
    float di = 1.0f;
    if (n < N) {
        int start = rowptr[n], end = rowptr[n + 1];
        di = dinv[n];
        float acc0 = z[(size_t)n * EM + c];   // self loop (pre-scaled)
        float acc1 = 0.0f;
        int j = start;
        for (; j + 1 < end; j += 2) {
            int s0 = col[j], s1 = col[j + 1];
            float w0 = w[j], w1 = w[j + 1];
            acc0 = fmaf(w0, z[(size_t)s0 * EM + c], acc0);
            acc1 = fmaf(w1, z[(size_t)s1 * EM + c], acc1);
        }
        if (j < end)
            acc0 = fmaf(w[j], z[(size_t)col[j] * EM + c], acc0);
        float acc = acc0 + acc1;
        float rc = 1.0f / (float)(end - start + 1);
        x = sp(fmaf(acc * di, rc, bconv[c]));
    }
    __syncthreads();      // sW ready
    lx[g][c] = x;
    __syncthreads();
    if (n < N) {
        if (mulW) {
            float a = 0.0f;
#pragma unroll
            for (int j = 0; j < EM; j++) a = fmaf(lx[g][j], sW[j * EM + c], a);
            xout[(size_t)n * EM + c] = a * di;   // pre-scale layer-2 operand
        } else {
            xout[(size_t)n * EM + c] = x;
        }
    }
}

// Kernel 7: dense heads: y = sp(x2 @ Wp1 + bp1); out = (y @ Wp2 + bp2)/sig.
__global__ __launch_bounds__(256) void node_out(
    const float* __restrict__ W_p1, const float* __restrict__ b_p1,
    const float* __restrict__ W_p2, const float* __restrict__ b_p2,
    const float* __restrict__ sig, const float* __restrict__ x2arr,
    float* __restrict__ out, int N)
{
    __shared__ float sP1[EM * EM];
    __shared__ float sbp1[EM];
    __shared__ float sP2[EM * ND];
    __shared__ float sbp2[ND];
    int t = threadIdx.x;
    sP1[t] = W_p1[t];
    if (t < EM)      sbp1[t] = b_p1[t];
    if (t < EM * ND) sP2[t] = W_p2[t];
    if (t < ND)      sbp2[t] = b_p2[t];
    __syncthreads();

    int n = blockIdx.x * 256 + t;
    if (n >= N) return;

    const float4* xp = (const float4*)(x2arr + (size_t)n * EM);
    float x2[EM];
#pragma unroll
    for (int q = 0; q < 4; q++) {
        float4 xv = xp[q];
        x2[4*q+0] = xv.x; x2[4*q+1] = xv.y; x2[4*q+2] = xv.z; x2[4*q+3] = xv.w;
    }
    float y[EM];
#pragma unroll
    for (int k = 0; k < EM; k++) {
        float a = sbp1[k];
#pragma unroll
        for (int j = 0; j < EM; j++) a = fmaf(x2[j], sP1[j * EM + k], a);
        y[k] = sp(a);
    }
    float rs = 1.0f / sig[n];
#pragma unroll
    for (int ch = 0; ch < ND; ch++) {
        float a = sbp2[ch];
#pragma unroll
        for (int j = 0; j < EM; j++) a = fmaf(y[j], sP2[j * ND + ch], a);
        out[(size_t)n * ND + ch] = a * rs;
    }
}

extern "C" void kernel_launch(void* const* d_in, const int* in_sizes, int n_in,
                              void* d_out, int out_size, void* d_ws, size_t ws_size,
                              hipStream_t stream) {
    const float* pos    = (const float*)d_in[0];
    const float* sig    = (const float*)d_in[1];
    const int*   ei     = (const int*)d_in[2];
    const float* W_init = (const float*)d_in[4];
    const float* b_init = (const float*)d_in[5];
    const float* W_g1   = (const float*)d_in[6];
    const float* b_g1   = (const float*)d_in[7];
    const float* W_g2   = (const float*)d_in[8];
    const float* b_g2   = (const float*)d_in[9];
    const float* W_p1   = (const float*)d_in[10];
    const float* b_p1   = (const float*)d_in[11];
    const float* W_p2   = (const float*)d_in[12];
    const float* b_p2   = (const float*)d_in[13];
    float* out = (float*)d_out;

    int N = in_sizes[0] / ND;
    int E = in_sizes[2] / 2;
    size_t Ns = (size_t)N, Es = (size_t)E;
    int NB = (N + BQ - 1) >> BQ_SH;   // <= MAXB for N <= 524288

    // Workspace layout (4B elements):
    // rowptr[N+1] | col[E] | bcnt[1024] | gbase[1024] | gcur[1024]
    //   | dinv[N] | xwA[16N] | xwB[16N] | wbuf[E]
    // packed pairs[E] (u32, 32MB) aliases xwA (dead before node_init).
    int* rowptr = (int*)d_ws;
    int* col    = rowptr + (Ns + 1);
    int* bcnt   = col + Es;
    int* gbase  = bcnt + 1024;
    int* gcur   = gbase + 1024;
    size_t off  = (Ns + 1) + Es + 3 * 1024;
    off = (off + 3) & ~(size_t)3;
    float* dinv = (float*)d_ws + off;
    size_t offA = off + Ns;
    offA = (offA + 3) & ~(size_t)3;
    float* xwA  = (float*)d_ws + offA;
    float* xwB  = xwA + Ns * EM;
    float* wbuf = xwB + Ns * EM;
    unsigned int* pairs = (unsigned int*)xwA;

    int nbN = (N + 255) / 256;
    int nbG = (N + 15) / 16;            // 16 nodes per 256-thread block
    int nbBin = (E + CHK - 1) / CHK;

    bucket_zero<<<1, 1024, 0, stream>>>(bcnt);
    bucket_count<<<1024, 256, 0, stream>>>(ei, bcnt, E, NB);
    bucket_scan<<<1, 1024, 0, stream>>>(bcnt, gbase, gcur, NB);
    edge_bin<<<nbBin, 256, 0, stream>>>(ei, gcur, pairs, E);
    bucket_csr<<<NB, 256, 0, stream>>>(pairs, gbase, bcnt, rowptr, col, N, NB);
    node_init<<<nbN, 256, 0, stream>>>(pos, W_init, b_init, W_g1, xwA, N);
    deg_gather<<<nbG, 256, 0, stream>>>(rowptr, col, pos, wbuf, dinv, xwA, N);
    gather_conv<<<nbG, 256, 0, stream>>>(rowptr, col, wbuf, dinv, xwA, b_g1, W_g2, xwB, N, 1);
    gather_conv<<<nbG, 256, 0, stream>>>(rowptr, col, wbuf, dinv, xwB, b_g2, W_g2, xwA, N, 0);
    node_out<<<nbN, 256, 0, stream>>>(W_p1, b_p1, W_p2, b_p2, sig, xwA, out, N);
}